// Round 1
// baseline (2383.177 us; speedup 1.0000x reference)
//
#include <hip/hip_runtime.h>

#define NG 128
#define G3 (NG*NG*NG)

__device__ __constant__ const float c_DX      = 1.0f/128.0f;
__device__ __constant__ const float c_INV_DX  = 128.0f;

#define DT      1e-4f
#define P_VOL   ((1.0f/256.0f)*(1.0f/256.0f))
#define P_MASS  P_VOL
#define MU0     (5000.0f/(2.0f*1.2f))
#define LAM0    (5000.0f*0.2f/(1.2f*0.6f))

// ---------------- 3x3 SVD via Jacobi on A^T A ----------------
__device__ inline void jacobi_rot(float S[3][3], float V[3][3], int p, int q) {
    float apq = S[p][q];
    if (fabsf(apq) < 1e-24f) return;
    float tau = (S[q][q] - S[p][p]) / (2.0f * apq);
    float t = copysignf(1.0f, tau) / (fabsf(tau) + sqrtf(1.0f + tau*tau));
    float c = rsqrtf(1.0f + t*t);
    float sn = t * c;
    // S <- J^T S J,  J[p][p]=c, J[p][q]=sn, J[q][p]=-sn, J[q][q]=c
    #pragma unroll
    for (int k = 0; k < 3; ++k) {
        float Spk = S[p][k], Sqk = S[q][k];
        S[p][k] = c*Spk - sn*Sqk;
        S[q][k] = sn*Spk + c*Sqk;
    }
    #pragma unroll
    for (int k = 0; k < 3; ++k) {
        float Skp = S[k][p], Skq = S[k][q];
        S[k][p] = c*Skp - sn*Skq;
        S[k][q] = sn*Skp + c*Skq;
    }
    #pragma unroll
    for (int k = 0; k < 3; ++k) {
        float Vkp = V[k][p], Vkq = V[k][q];
        V[k][p] = c*Vkp - sn*Vkq;
        V[k][q] = sn*Vkp + c*Vkq;
    }
}

// A row-major [9]. Outputs U[9], sv[3] descending, V[9] (columns = right sing. vecs)
__device__ inline void svd3(const float A[9], float U[9], float sv[3], float V[9]) {
    float S[3][3];
    #pragma unroll
    for (int i = 0; i < 3; ++i)
        #pragma unroll
        for (int j = 0; j < 3; ++j) {
            float acc = 0.f;
            #pragma unroll
            for (int k = 0; k < 3; ++k) acc += A[k*3+i]*A[k*3+j];
            S[i][j] = acc;
        }
    float Vm[3][3] = {{1.f,0.f,0.f},{0.f,1.f,0.f},{0.f,0.f,1.f}};
    #pragma unroll
    for (int sweep = 0; sweep < 4; ++sweep) {
        jacobi_rot(S, Vm, 0, 1);
        jacobi_rot(S, Vm, 0, 2);
        jacobi_rot(S, Vm, 1, 2);
    }
    float lam[3] = {S[0][0], S[1][1], S[2][2]};
    int i0 = 0, i1 = 1, i2 = 2, t;
    if (lam[i0] < lam[i1]) { t = i0; i0 = i1; i1 = t; }
    if (lam[i0] < lam[i2]) { t = i0; i0 = i2; i2 = t; }
    if (lam[i1] < lam[i2]) { t = i1; i1 = i2; i2 = t; }
    int ord[3] = {i0, i1, i2};
    #pragma unroll
    for (int c = 0; c < 3; ++c) {
        int s_ = ord[c];
        float l = fmaxf(lam[s_], 0.f);
        float sval = sqrtf(l);
        sv[c] = sval;
        float v0 = Vm[0][s_], v1 = Vm[1][s_], v2 = Vm[2][s_];
        V[0*3+c] = v0; V[1*3+c] = v1; V[2*3+c] = v2;
        float inv = (sval > 1e-12f) ? 1.0f/sval : 0.f;
        U[0*3+c] = (A[0]*v0 + A[1]*v1 + A[2]*v2)*inv;
        U[1*3+c] = (A[3]*v0 + A[4]*v1 + A[5]*v2)*inv;
        U[2*3+c] = (A[6]*v0 + A[7]*v1 + A[8]*v2)*inv;
    }
}

// ---------------- P2G ----------------
__global__ void __launch_bounds__(256)
p2g_kernel(const float* __restrict__ x, const float* __restrict__ v,
           const float* __restrict__ Cin, const float* __restrict__ Fin,
           const float* __restrict__ Jp_in, const int* __restrict__ material,
           float4* __restrict__ grid, float* __restrict__ out, int N) {
    int n = blockIdx.x * 256 + threadIdx.x;
    if (n >= N) return;

    float px = x[3*n+0], py = x[3*n+1], pz = x[3*n+2];
    float bxf = floorf(px*c_INV_DX - 0.5f);
    float byf = floorf(py*c_INV_DX - 0.5f);
    float bzf = floorf(pz*c_INV_DX - 0.5f);
    int bi = (int)bxf, bj = (int)byf, bk = (int)bzf;
    // safety clamp (no-op for valid data)
    bi = min(max(bi, 0), NG-3); bj = min(max(bj, 0), NG-3); bk = min(max(bk, 0), NG-3);
    float fx0 = px*c_INV_DX - bxf;
    float fx1 = py*c_INV_DX - byf;
    float fx2 = pz*c_INV_DX - bzf;

    float wx[3], wy[3];
    wx[0] = 0.5f*(1.5f-fx0)*(1.5f-fx0); wx[1] = 0.75f-(fx0-1.f)*(fx0-1.f); wx[2] = 0.5f*(fx0-0.5f)*(fx0-0.5f);
    wy[0] = 0.5f*(1.5f-fx1)*(1.5f-fx1); wy[1] = 0.75f-(fx1-1.f)*(fx1-1.f); wy[2] = 0.5f*(fx1-0.5f)*(fx1-0.5f);

    float Cm[9], Fm[9];
    #pragma unroll
    for (int i = 0; i < 9; ++i) { Cm[i] = Cin[9*n+i]; Fm[i] = Fin[9*n+i]; }

    // Fn = (I + DT*C) @ F
    float Fn[9];
    #pragma unroll
    for (int i = 0; i < 3; ++i)
        #pragma unroll
        for (int k = 0; k < 3; ++k) {
            float acc = Fm[i*3+k];
            #pragma unroll
            for (int j = 0; j < 3; ++j) acc += DT * Cm[i*3+j] * Fm[j*3+k];
            Fn[i*3+k] = acc;
        }

    float Jp = Jp_in[n];
    int mat = material[n];
    float h = expf(10.0f*(1.0f - Jp));
    h = fminf(fmaxf(h, 0.1f), 5.0f);
    if (mat == 1) h = 0.3f;
    float mu = (mat == 0) ? 0.0f : MU0*h;
    float la = LAM0*h;

    float U[9], V[9], sv[3];
    svd3(Fn, U, sv, V);

    float J = 1.0f;
    float sig[3];
    #pragma unroll
    for (int d = 0; d < 2; ++d) {
        float s = sv[d];
        float ns = (mat == 2) ? fminf(fmaxf(s, 1.0f-0.025f), 1.0f+0.0045f) : s;
        Jp = Jp * s / ns;
        sig[d] = ns;
        J *= ns;
    }
    sig[2] = sv[2];

    if (mat == 0) {
        float sj = sqrtf(J);
        Fn[0]=sj; Fn[1]=0; Fn[2]=0; Fn[3]=0; Fn[4]=sj; Fn[5]=0; Fn[6]=0; Fn[7]=0; Fn[8]=sj;
    } else if (mat == 2) {
        // Fn = U diag(sig) V^T
        #pragma unroll
        for (int i = 0; i < 3; ++i)
            #pragma unroll
            for (int k = 0; k < 3; ++k) {
                float acc = 0.f;
                #pragma unroll
                for (int j = 0; j < 3; ++j) acc += U[i*3+j]*sig[j]*V[k*3+j];
                Fn[i*3+k] = acc;
            }
    }

    // R = U V^T
    float R[9];
    #pragma unroll
    for (int i = 0; i < 3; ++i)
        #pragma unroll
        for (int k = 0; k < 3; ++k) {
            float acc = 0.f;
            #pragma unroll
            for (int j = 0; j < 3; ++j) acc += U[i*3+j]*V[k*3+j];
            R[i*3+k] = acc;
        }

    // stress = 2*mu*(Fn-R)@Fn^T + I*(la*J*(J-1)); scaled; affine = stress + P_MASS*C
    float press = la * J * (J - 1.0f);
    float scale = -DT * P_VOL * 4.0f * c_INV_DX * c_INV_DX;
    float aff[9];
    #pragma unroll
    for (int i = 0; i < 3; ++i)
        #pragma unroll
        for (int k = 0; k < 3; ++k) {
            float acc = 0.f;
            #pragma unroll
            for (int j = 0; j < 3; ++j) acc += (Fn[i*3+j]-R[i*3+j])*Fn[k*3+j];
            acc = 2.0f*mu*acc;
            if (i == k) acc += press;
            aff[i*3+k] = scale*acc + P_MASS*Cm[i*3+k];
        }

    // outputs computed here
    float* po = out + (size_t)n*25;
    po[6] = Jp;
    #pragma unroll
    for (int i = 0; i < 9; ++i) po[7+i] = Fn[i];

    float mv0 = P_MASS*v[3*n+0], mv1 = P_MASS*v[3*n+1], mv2 = P_MASS*v[3*n+2];

    #pragma unroll
    for (int i = 0; i < 3; ++i) {
        float dpx = ((float)i - fx0)*c_DX;
        #pragma unroll
        for (int j = 0; j < 3; ++j) {
            float wgt = wx[i]*wy[j];           // NOTE: reference uses only x,y weights
            float dpy = ((float)j - fx1)*c_DX;
            int cell0 = ((bi+i)*NG + (bj+j))*NG + bk;
            float wm = wgt*P_MASS;
            #pragma unroll
            for (int k = 0; k < 3; ++k) {
                float dpz = ((float)k - fx2)*c_DX;
                float mx = wgt*(mv0 + aff[0]*dpx + aff[1]*dpy + aff[2]*dpz);
                float my = wgt*(mv1 + aff[3]*dpx + aff[4]*dpy + aff[5]*dpz);
                float mz = wgt*(mv2 + aff[6]*dpx + aff[7]*dpy + aff[8]*dpz);
                float* cp = (float*)&grid[cell0 + k];
                atomicAdd(cp+0, mx);
                atomicAdd(cp+1, my);
                atomicAdd(cp+2, mz);
                atomicAdd(cp+3, wm);
            }
        }
    }
}

// ---------------- grid update ----------------
__global__ void __launch_bounds__(256)
grid_kernel(float4* __restrict__ grid, const float* __restrict__ gravity,
            const float* __restrict__ attr_s, const float* __restrict__ attr_p) {
    int g = blockIdx.x * 256 + threadIdx.x;
    if (g >= G3) return;
    float4 cell = grid[g];
    float m = cell.w;
    float gvx = 0.f, gvy = 0.f, gvz = 0.f;
    if (m > 0.f) {
        float inv = 1.0f/m;
        gvx = cell.x*inv; gvy = cell.y*inv; gvz = cell.z*inv;
        gvx += DT * gravity[0] * 30.0f;
        gvy += DT * gravity[1] * 30.0f;
        gvz += DT * gravity[2] * 30.0f;
        int k = g & (NG-1);
        int j = (g >> 7) & (NG-1);
        int i = g >> 14;
        float dx_ = attr_p[0] - c_DX*(float)i;
        float dy_ = attr_p[1] - c_DX*(float)j;
        float dz_ = attr_p[2] - c_DX*(float)k;
        float nrm = sqrtf(dx_*dx_ + dy_*dy_ + dz_*dz_);
        float sc = attr_s[0] * DT * 100.0f / (0.01f + nrm);
        gvx += dx_*sc; gvy += dy_*sc; gvz += dz_*sc;
        if (i < 3      && gvx < 0.f) gvx = 0.f;
        if (i > NG-3   && gvx > 0.f) gvx = 0.f;
        if (j < 3      && gvy < 0.f) gvy = 0.f;
        if (j > NG-3   && gvy > 0.f) gvy = 0.f;
        // z unconstrained (matches reference)
    }
    grid[g] = make_float4(gvx, gvy, gvz, m);
}

// ---------------- G2P ----------------
__global__ void __launch_bounds__(256)
g2p_kernel(const float* __restrict__ x, const float4* __restrict__ grid,
           float* __restrict__ out, int N) {
    int n = blockIdx.x * 256 + threadIdx.x;
    if (n >= N) return;

    float px = x[3*n+0], py = x[3*n+1], pz = x[3*n+2];
    float bxf = floorf(px*c_INV_DX - 0.5f);
    float byf = floorf(py*c_INV_DX - 0.5f);
    float bzf = floorf(pz*c_INV_DX - 0.5f);
    int bi = (int)bxf, bj = (int)byf, bk = (int)bzf;
    bi = min(max(bi, 0), NG-3); bj = min(max(bj, 0), NG-3); bk = min(max(bk, 0), NG-3);
    float fx0 = px*c_INV_DX - bxf;
    float fx1 = py*c_INV_DX - byf;
    float fx2 = pz*c_INV_DX - bzf;

    float wx[3], wy[3];
    wx[0] = 0.5f*(1.5f-fx0)*(1.5f-fx0); wx[1] = 0.75f-(fx0-1.f)*(fx0-1.f); wx[2] = 0.5f*(fx0-0.5f)*(fx0-0.5f);
    wy[0] = 0.5f*(1.5f-fx1)*(1.5f-fx1); wy[1] = 0.75f-(fx1-1.f)*(fx1-1.f); wy[2] = 0.5f*(fx1-0.5f)*(fx1-0.5f);

    float nvx = 0.f, nvy = 0.f, nvz = 0.f;
    float nC[9];
    #pragma unroll
    for (int i = 0; i < 9; ++i) nC[i] = 0.f;

    #pragma unroll
    for (int i = 0; i < 3; ++i) {
        float dpx = (float)i - fx0;
        #pragma unroll
        for (int j = 0; j < 3; ++j) {
            float wgt = wx[i]*wy[j];
            float dpy = (float)j - fx1;
            int cell0 = ((bi+i)*NG + (bj+j))*NG + bk;
            #pragma unroll
            for (int k = 0; k < 3; ++k) {
                float dpz = (float)k - fx2;
                float4 gv = grid[cell0 + k];
                float wgx = wgt*gv.x, wgy = wgt*gv.y, wgz = wgt*gv.z;
                nvx += wgx; nvy += wgy; nvz += wgz;
                nC[0] += wgx*dpx; nC[1] += wgx*dpy; nC[2] += wgx*dpz;
                nC[3] += wgy*dpx; nC[4] += wgy*dpy; nC[5] += wgy*dpz;
                nC[6] += wgz*dpx; nC[7] += wgz*dpy; nC[8] += wgz*dpz;
            }
        }
    }

    float* po = out + (size_t)n*25;
    po[0] = px + DT*nvx;
    po[1] = py + DT*nvy;
    po[2] = pz + DT*nvz;
    po[3] = nvx; po[4] = nvy; po[5] = nvz;
    float s4 = 4.0f*c_INV_DX;
    #pragma unroll
    for (int i = 0; i < 9; ++i) po[16+i] = s4*nC[i];
}

extern "C" void kernel_launch(void* const* d_in, const int* in_sizes, int n_in,
                              void* d_out, int out_size, void* d_ws, size_t ws_size,
                              hipStream_t stream) {
    const float* x        = (const float*)d_in[0];
    const float* v        = (const float*)d_in[1];
    const float* C        = (const float*)d_in[2];
    const float* F        = (const float*)d_in[3];
    const float* Jp       = (const float*)d_in[4];
    const float* gravity  = (const float*)d_in[5];
    const float* attr_s   = (const float*)d_in[6];
    const float* attr_p   = (const float*)d_in[7];
    const int*   material = (const int*)d_in[8];
    float* out = (float*)d_out;
    int N = in_sizes[0] / 3;

    float4* grid = (float4*)d_ws;
    hipMemsetAsync(d_ws, 0, (size_t)G3 * sizeof(float4), stream);

    int pblocks = (N + 255) / 256;
    p2g_kernel<<<pblocks, 256, 0, stream>>>(x, v, C, F, Jp, material, grid, out, N);
    grid_kernel<<<G3/256, 256, 0, stream>>>(grid, gravity, attr_s, attr_p);
    g2p_kernel<<<pblocks, 256, 0, stream>>>(x, grid, out, N);
}

// Round 2
// 555.686 us; speedup vs baseline: 4.2887x; 4.2887x over previous
//
#include <hip/hip_runtime.h>

#define NG 128
#define G3 (NG*NG*NG)
#define NT 16               // tiles per axis (8 cells per tile)
#define NTILES (NT*NT*NT)   // 4096

__device__ __constant__ const float c_DX      = 1.0f/128.0f;
__device__ __constant__ const float c_INV_DX  = 128.0f;

#define DT      1e-4f
#define P_VOL   ((1.0f/256.0f)*(1.0f/256.0f))
#define P_MASS  P_VOL
#define MU0     (5000.0f/(2.0f*1.2f))
#define LAM0    (5000.0f*0.2f/(1.2f*0.6f))

// ---------------- 3x3 SVD via Jacobi on A^T A ----------------
__device__ inline void jacobi_rot(float S[3][3], float V[3][3], int p, int q) {
    float apq = S[p][q];
    if (fabsf(apq) < 1e-24f) return;
    float tau = (S[q][q] - S[p][p]) / (2.0f * apq);
    float t = copysignf(1.0f, tau) / (fabsf(tau) + sqrtf(1.0f + tau*tau));
    float c = rsqrtf(1.0f + t*t);
    float sn = t * c;
    #pragma unroll
    for (int k = 0; k < 3; ++k) {
        float Spk = S[p][k], Sqk = S[q][k];
        S[p][k] = c*Spk - sn*Sqk;
        S[q][k] = sn*Spk + c*Sqk;
    }
    #pragma unroll
    for (int k = 0; k < 3; ++k) {
        float Skp = S[k][p], Skq = S[k][q];
        S[k][p] = c*Skp - sn*Skq;
        S[k][q] = sn*Skp + c*Skq;
    }
    #pragma unroll
    for (int k = 0; k < 3; ++k) {
        float Vkp = V[k][p], Vkq = V[k][q];
        V[k][p] = c*Vkp - sn*Vkq;
        V[k][q] = sn*Vkp + c*Vkq;
    }
}

__device__ inline void svd3(const float A[9], float U[9], float sv[3], float V[9]) {
    float S[3][3];
    #pragma unroll
    for (int i = 0; i < 3; ++i)
        #pragma unroll
        for (int j = 0; j < 3; ++j) {
            float acc = 0.f;
            #pragma unroll
            for (int k = 0; k < 3; ++k) acc += A[k*3+i]*A[k*3+j];
            S[i][j] = acc;
        }
    float Vm[3][3] = {{1.f,0.f,0.f},{0.f,1.f,0.f},{0.f,0.f,1.f}};
    #pragma unroll
    for (int sweep = 0; sweep < 4; ++sweep) {
        jacobi_rot(S, Vm, 0, 1);
        jacobi_rot(S, Vm, 0, 2);
        jacobi_rot(S, Vm, 1, 2);
    }
    float lam[3] = {S[0][0], S[1][1], S[2][2]};
    int i0 = 0, i1 = 1, i2 = 2, t;
    if (lam[i0] < lam[i1]) { t = i0; i0 = i1; i1 = t; }
    if (lam[i0] < lam[i2]) { t = i0; i0 = i2; i2 = t; }
    if (lam[i1] < lam[i2]) { t = i1; i1 = i2; i2 = t; }
    int ord[3] = {i0, i1, i2};
    #pragma unroll
    for (int c = 0; c < 3; ++c) {
        int s_ = ord[c];
        float l = fmaxf(lam[s_], 0.f);
        float sval = sqrtf(l);
        sv[c] = sval;
        float v0 = Vm[0][s_], v1 = Vm[1][s_], v2 = Vm[2][s_];
        V[0*3+c] = v0; V[1*3+c] = v1; V[2*3+c] = v2;
        float inv = (sval > 1e-12f) ? 1.0f/sval : 0.f;
        U[0*3+c] = (A[0]*v0 + A[1]*v1 + A[2]*v2)*inv;
        U[1*3+c] = (A[3]*v0 + A[4]*v1 + A[5]*v2)*inv;
        U[2*3+c] = (A[6]*v0 + A[7]*v1 + A[8]*v2)*inv;
    }
}

// ---------------- binning ----------------
__device__ inline int particle_tile(const float* __restrict__ x, int n) {
    float px = x[3*n+0], py = x[3*n+1], pz = x[3*n+2];
    int bi = (int)floorf(px*c_INV_DX - 0.5f);
    int bj = (int)floorf(py*c_INV_DX - 0.5f);
    int bk = (int)floorf(pz*c_INV_DX - 0.5f);
    bi = min(max(bi, 0), NG-3); bj = min(max(bj, 0), NG-3); bk = min(max(bk, 0), NG-3);
    return ((bi >> 3)*NT + (bj >> 3))*NT + (bk >> 3);
}

__global__ void __launch_bounds__(256)
count_kernel(const float* __restrict__ x, int* __restrict__ tile_count, int N) {
    int n = blockIdx.x*256 + threadIdx.x;
    if (n >= N) return;
    atomicAdd(&tile_count[particle_tile(x, n)], 1);
}

// exclusive scan of 4096 tile counts, single block of 256 threads x 16 elems
__global__ void __launch_bounds__(256)
scan_kernel(const int* __restrict__ count, int* __restrict__ offset) {
    __shared__ int part[256];
    int t = threadIdx.x;
    int base = t*16;
    int local[16];
    int s = 0;
    #pragma unroll
    for (int i = 0; i < 16; ++i) { local[i] = s; s += count[base+i]; }
    part[t] = s;
    __syncthreads();
    for (int off = 1; off < 256; off <<= 1) {
        int v = (t >= off) ? part[t-off] : 0;
        __syncthreads();
        part[t] += v;
        __syncthreads();
    }
    int prev = (t == 0) ? 0 : part[t-1];
    #pragma unroll
    for (int i = 0; i < 16; ++i) offset[base+i] = prev + local[i];
    if (t == 255) offset[NTILES] = prev + s;
}

__global__ void __launch_bounds__(256)
bin_kernel(const float* __restrict__ x, const int* __restrict__ offset,
           int* __restrict__ cursor, int* __restrict__ sorted, int N) {
    int n = blockIdx.x*256 + threadIdx.x;
    if (n >= N) return;
    int t = particle_tile(x, n);
    int pos = atomicAdd(&cursor[t], 1);
    sorted[offset[t] + pos] = n;
}

// ---------------- P2G (tiled, LDS accumulate) ----------------
__global__ void __launch_bounds__(256)
p2g_tile_kernel(const float* __restrict__ x, const float* __restrict__ v,
                const float* __restrict__ Cin, const float* __restrict__ Fin,
                const float* __restrict__ Jp_in, const int* __restrict__ material,
                const int* __restrict__ sorted, const int* __restrict__ offset,
                float4* __restrict__ grid, float* __restrict__ out) {
    int tile = blockIdx.x;
    int beg = offset[tile], end = offset[tile+1];
    if (beg == end) return;

    __shared__ float lds[4][1000];   // SoA: [comp][10*10*10 halo cells]
    for (int c = threadIdx.x; c < 1000; c += 256) {
        lds[0][c] = 0.f; lds[1][c] = 0.f; lds[2][c] = 0.f; lds[3][c] = 0.f;
    }
    __syncthreads();

    int tx8 = (tile / (NT*NT)) << 3;
    int ty8 = ((tile / NT) % NT) << 3;
    int tz8 = (tile % NT) << 3;

    for (int p = beg + (int)threadIdx.x; p < end; p += 256) {
        int n = sorted[p];

        float px = x[3*n+0], py = x[3*n+1], pz = x[3*n+2];
        float bxf = floorf(px*c_INV_DX - 0.5f);
        float byf = floorf(py*c_INV_DX - 0.5f);
        float bzf = floorf(pz*c_INV_DX - 0.5f);
        int bi = (int)bxf, bj = (int)byf, bk = (int)bzf;
        bi = min(max(bi, 0), NG-3); bj = min(max(bj, 0), NG-3); bk = min(max(bk, 0), NG-3);
        float fx0 = px*c_INV_DX - bxf;
        float fx1 = py*c_INV_DX - byf;
        float fx2 = pz*c_INV_DX - bzf;

        float wx[3], wy[3];
        wx[0] = 0.5f*(1.5f-fx0)*(1.5f-fx0); wx[1] = 0.75f-(fx0-1.f)*(fx0-1.f); wx[2] = 0.5f*(fx0-0.5f)*(fx0-0.5f);
        wy[0] = 0.5f*(1.5f-fx1)*(1.5f-fx1); wy[1] = 0.75f-(fx1-1.f)*(fx1-1.f); wy[2] = 0.5f*(fx1-0.5f)*(fx1-0.5f);

        float Cm[9], Fm[9];
        #pragma unroll
        for (int i = 0; i < 9; ++i) { Cm[i] = Cin[9*n+i]; Fm[i] = Fin[9*n+i]; }

        float Fn[9];
        #pragma unroll
        for (int i = 0; i < 3; ++i)
            #pragma unroll
            for (int k = 0; k < 3; ++k) {
                float acc = Fm[i*3+k];
                #pragma unroll
                for (int j = 0; j < 3; ++j) acc += DT * Cm[i*3+j] * Fm[j*3+k];
                Fn[i*3+k] = acc;
            }

        float Jp = Jp_in[n];
        int mat = material[n];
        float h = expf(10.0f*(1.0f - Jp));
        h = fminf(fmaxf(h, 0.1f), 5.0f);
        if (mat == 1) h = 0.3f;
        float mu = (mat == 0) ? 0.0f : MU0*h;
        float la = LAM0*h;

        float U[9], V[9], sv[3];
        svd3(Fn, U, sv, V);

        float J = 1.0f;
        float sig[3];
        #pragma unroll
        for (int d = 0; d < 2; ++d) {
            float s = sv[d];
            float ns = (mat == 2) ? fminf(fmaxf(s, 1.0f-0.025f), 1.0f+0.0045f) : s;
            Jp = Jp * s / ns;
            sig[d] = ns;
            J *= ns;
        }
        sig[2] = sv[2];

        if (mat == 0) {
            float sj = sqrtf(J);
            Fn[0]=sj; Fn[1]=0; Fn[2]=0; Fn[3]=0; Fn[4]=sj; Fn[5]=0; Fn[6]=0; Fn[7]=0; Fn[8]=sj;
        } else if (mat == 2) {
            #pragma unroll
            for (int i = 0; i < 3; ++i)
                #pragma unroll
                for (int k = 0; k < 3; ++k) {
                    float acc = 0.f;
                    #pragma unroll
                    for (int j = 0; j < 3; ++j) acc += U[i*3+j]*sig[j]*V[k*3+j];
                    Fn[i*3+k] = acc;
                }
        }

        float R[9];
        #pragma unroll
        for (int i = 0; i < 3; ++i)
            #pragma unroll
            for (int k = 0; k < 3; ++k) {
                float acc = 0.f;
                #pragma unroll
                for (int j = 0; j < 3; ++j) acc += U[i*3+j]*V[k*3+j];
                R[i*3+k] = acc;
            }

        float press = la * J * (J - 1.0f);
        float scale = -DT * P_VOL * 4.0f * c_INV_DX * c_INV_DX;
        float aff[9];
        #pragma unroll
        for (int i = 0; i < 3; ++i)
            #pragma unroll
            for (int k = 0; k < 3; ++k) {
                float acc = 0.f;
                #pragma unroll
                for (int j = 0; j < 3; ++j) acc += (Fn[i*3+j]-R[i*3+j])*Fn[k*3+j];
                acc = 2.0f*mu*acc;
                if (i == k) acc += press;
                aff[i*3+k] = scale*acc + P_MASS*Cm[i*3+k];
            }

        float* po = out + (size_t)n*25;
        po[6] = Jp;
        #pragma unroll
        for (int i = 0; i < 9; ++i) po[7+i] = Fn[i];

        float mv0 = P_MASS*v[3*n+0], mv1 = P_MASS*v[3*n+1], mv2 = P_MASS*v[3*n+2];

        int offi = bi - tx8, offj = bj - ty8, offk = bk - tz8;
        #pragma unroll
        for (int i = 0; i < 3; ++i) {
            float dpx = ((float)i - fx0)*c_DX;
            #pragma unroll
            for (int j = 0; j < 3; ++j) {
                float wgt = wx[i]*wy[j];     // reference uses only x,y weight factors
                float dpy = ((float)j - fx1)*c_DX;
                int c0 = ((offi+i)*10 + (offj+j))*10 + offk;
                float wm = wgt*P_MASS;
                #pragma unroll
                for (int k = 0; k < 3; ++k) {
                    float dpz = ((float)k - fx2)*c_DX;
                    float mx = wgt*(mv0 + aff[0]*dpx + aff[1]*dpy + aff[2]*dpz);
                    float my = wgt*(mv1 + aff[3]*dpx + aff[4]*dpy + aff[5]*dpz);
                    float mz = wgt*(mv2 + aff[6]*dpx + aff[7]*dpy + aff[8]*dpz);
                    int c = c0 + k;
                    atomicAdd(&lds[0][c], mx);
                    atomicAdd(&lds[1][c], my);
                    atomicAdd(&lds[2][c], mz);
                    atomicAdd(&lds[3][c], wm);
                }
            }
        }
    }
    __syncthreads();

    // dense flush of the 10x10x10 halo region
    for (int c = threadIdx.x; c < 1000; c += 256) {
        float gm = lds[3][c];
        float gx = lds[0][c], gy = lds[1][c], gz = lds[2][c];
        if (gm != 0.f || gx != 0.f || gy != 0.f || gz != 0.f) {
            int ci = c / 100, cj = (c / 10) % 10, ck = c % 10;
            int gi = tx8 + ci, gj = ty8 + cj, gk = tz8 + ck;
            if (gi < NG && gj < NG && gk < NG) {
                float* cp = (float*)&grid[(gi*NG + gj)*NG + gk];
                atomicAdd(cp+0, gx);
                atomicAdd(cp+1, gy);
                atomicAdd(cp+2, gz);
                atomicAdd(cp+3, gm);
            }
        }
    }
}

// ---------------- grid update ----------------
__global__ void __launch_bounds__(256)
grid_kernel(float4* __restrict__ grid, const float* __restrict__ gravity,
            const float* __restrict__ attr_s, const float* __restrict__ attr_p) {
    int g = blockIdx.x * 256 + threadIdx.x;
    if (g >= G3) return;
    float4 cell = grid[g];
    float m = cell.w;
    float gvx = 0.f, gvy = 0.f, gvz = 0.f;
    if (m > 0.f) {
        float inv = 1.0f/m;
        gvx = cell.x*inv; gvy = cell.y*inv; gvz = cell.z*inv;
        gvx += DT * gravity[0] * 30.0f;
        gvy += DT * gravity[1] * 30.0f;
        gvz += DT * gravity[2] * 30.0f;
        int k = g & (NG-1);
        int j = (g >> 7) & (NG-1);
        int i = g >> 14;
        float dx_ = attr_p[0] - c_DX*(float)i;
        float dy_ = attr_p[1] - c_DX*(float)j;
        float dz_ = attr_p[2] - c_DX*(float)k;
        float nrm = sqrtf(dx_*dx_ + dy_*dy_ + dz_*dz_);
        float sc = attr_s[0] * DT * 100.0f / (0.01f + nrm);
        gvx += dx_*sc; gvy += dy_*sc; gvz += dz_*sc;
        if (i < 3      && gvx < 0.f) gvx = 0.f;
        if (i > NG-3   && gvx > 0.f) gvx = 0.f;
        if (j < 3      && gvy < 0.f) gvy = 0.f;
        if (j > NG-3   && gvy > 0.f) gvy = 0.f;
    }
    grid[g] = make_float4(gvx, gvy, gvz, m);
}

// ---------------- G2P (sorted order for grid-gather locality) ----------------
__global__ void __launch_bounds__(256)
g2p_kernel(const float* __restrict__ x, const float4* __restrict__ grid,
           const int* __restrict__ sorted, float* __restrict__ out, int N) {
    int gid = blockIdx.x * 256 + threadIdx.x;
    if (gid >= N) return;
    int n = sorted[gid];

    float px = x[3*n+0], py = x[3*n+1], pz = x[3*n+2];
    float bxf = floorf(px*c_INV_DX - 0.5f);
    float byf = floorf(py*c_INV_DX - 0.5f);
    float bzf = floorf(pz*c_INV_DX - 0.5f);
    int bi = (int)bxf, bj = (int)byf, bk = (int)bzf;
    bi = min(max(bi, 0), NG-3); bj = min(max(bj, 0), NG-3); bk = min(max(bk, 0), NG-3);
    float fx0 = px*c_INV_DX - bxf;
    float fx1 = py*c_INV_DX - byf;
    float fx2 = pz*c_INV_DX - bzf;

    float wx[3], wy[3];
    wx[0] = 0.5f*(1.5f-fx0)*(1.5f-fx0); wx[1] = 0.75f-(fx0-1.f)*(fx0-1.f); wx[2] = 0.5f*(fx0-0.5f)*(fx0-0.5f);
    wy[0] = 0.5f*(1.5f-fx1)*(1.5f-fx1); wy[1] = 0.75f-(fx1-1.f)*(fx1-1.f); wy[2] = 0.5f*(fx1-0.5f)*(fx1-0.5f);

    float nvx = 0.f, nvy = 0.f, nvz = 0.f;
    float nC[9];
    #pragma unroll
    for (int i = 0; i < 9; ++i) nC[i] = 0.f;

    #pragma unroll
    for (int i = 0; i < 3; ++i) {
        float dpx = (float)i - fx0;
        #pragma unroll
        for (int j = 0; j < 3; ++j) {
            float wgt = wx[i]*wy[j];
            float dpy = (float)j - fx1;
            int cell0 = ((bi+i)*NG + (bj+j))*NG + bk;
            #pragma unroll
            for (int k = 0; k < 3; ++k) {
                float dpz = (float)k - fx2;
                float4 gv = grid[cell0 + k];
                float wgx = wgt*gv.x, wgy = wgt*gv.y, wgz = wgt*gv.z;
                nvx += wgx; nvy += wgy; nvz += wgz;
                nC[0] += wgx*dpx; nC[1] += wgx*dpy; nC[2] += wgx*dpz;
                nC[3] += wgy*dpx; nC[4] += wgy*dpy; nC[5] += wgy*dpz;
                nC[6] += wgz*dpx; nC[7] += wgz*dpy; nC[8] += wgz*dpz;
            }
        }
    }

    float* po = out + (size_t)n*25;
    po[0] = px + DT*nvx;
    po[1] = py + DT*nvy;
    po[2] = pz + DT*nvz;
    po[3] = nvx; po[4] = nvy; po[5] = nvz;
    float s4 = 4.0f*c_INV_DX;
    #pragma unroll
    for (int i = 0; i < 9; ++i) po[16+i] = s4*nC[i];
}

extern "C" void kernel_launch(void* const* d_in, const int* in_sizes, int n_in,
                              void* d_out, int out_size, void* d_ws, size_t ws_size,
                              hipStream_t stream) {
    const float* x        = (const float*)d_in[0];
    const float* v        = (const float*)d_in[1];
    const float* C        = (const float*)d_in[2];
    const float* F        = (const float*)d_in[3];
    const float* Jp       = (const float*)d_in[4];
    const float* gravity  = (const float*)d_in[5];
    const float* attr_s   = (const float*)d_in[6];
    const float* attr_p   = (const float*)d_in[7];
    const int*   material = (const int*)d_in[8];
    float* out = (float*)d_out;
    int N = in_sizes[0] / 3;

    // workspace layout: [grid][tile_count][cursor][tile_offset][sorted]
    char* ws = (char*)d_ws;
    float4* grid      = (float4*)ws;                       size_t o = (size_t)G3*sizeof(float4);
    int* tile_count   = (int*)(ws + o);                    o += NTILES*sizeof(int);
    int* cursor       = (int*)(ws + o);                    o += NTILES*sizeof(int);
    size_t zero_bytes = o;                                 // grid + counts + cursor zeroed in one memset
    int* tile_offset  = (int*)(ws + o);                    o += (NTILES+1)*sizeof(int);
    int* sorted       = (int*)(ws + o);                    o += (size_t)N*sizeof(int);

    hipMemsetAsync(d_ws, 0, zero_bytes, stream);

    int pblocks = (N + 255) / 256;
    count_kernel<<<pblocks, 256, 0, stream>>>(x, tile_count, N);
    scan_kernel<<<1, 256, 0, stream>>>(tile_count, tile_offset);
    bin_kernel<<<pblocks, 256, 0, stream>>>(x, tile_offset, cursor, sorted, N);
    p2g_tile_kernel<<<NTILES, 256, 0, stream>>>(x, v, C, F, Jp, material,
                                                sorted, tile_offset, grid, out);
    grid_kernel<<<G3/256, 256, 0, stream>>>(grid, gravity, attr_s, attr_p);
    g2p_kernel<<<pblocks, 256, 0, stream>>>(x, grid, sorted, out, N);
}

// Round 3
// 547.507 us; speedup vs baseline: 4.3528x; 1.0149x over previous
//
#include <hip/hip_runtime.h>

#define NG 128
#define G3 (NG*NG*NG)
#define NT 16               // tiles per axis (8 cells per tile)
#define NTILES (NT*NT*NT)   // 4096

__device__ __constant__ const float c_DX      = 1.0f/128.0f;
__device__ __constant__ const float c_INV_DX  = 128.0f;

#define DT      1e-4f
#define P_VOL   ((1.0f/256.0f)*(1.0f/256.0f))
#define P_MASS  P_VOL
#define MU0     (5000.0f/(2.0f*1.2f))
#define LAM0    (5000.0f*0.2f/(1.2f*0.6f))

// 64-byte packed particle record, written in sorted order
struct __align__(16) PRec {
    float px, py, pz;
    int   base;          // bi | bj<<7 | bk<<14
    float aff[9];
    float mv0, mv1, mv2;
};

// ---------------- 3x3 SVD via Jacobi on A^T A ----------------
__device__ inline void jacobi_rot(float S[3][3], float V[3][3], int p, int q) {
    float apq = S[p][q];
    if (fabsf(apq) < 1e-24f) return;
    float tau = (S[q][q] - S[p][p]) / (2.0f * apq);
    float t = copysignf(1.0f, tau) / (fabsf(tau) + sqrtf(1.0f + tau*tau));
    float c = rsqrtf(1.0f + t*t);
    float sn = t * c;
    #pragma unroll
    for (int k = 0; k < 3; ++k) {
        float Spk = S[p][k], Sqk = S[q][k];
        S[p][k] = c*Spk - sn*Sqk;
        S[q][k] = sn*Spk + c*Sqk;
    }
    #pragma unroll
    for (int k = 0; k < 3; ++k) {
        float Skp = S[k][p], Skq = S[k][q];
        S[k][p] = c*Skp - sn*Skq;
        S[k][q] = sn*Skp + c*Skq;
    }
    #pragma unroll
    for (int k = 0; k < 3; ++k) {
        float Vkp = V[k][p], Vkq = V[k][q];
        V[k][p] = c*Vkp - sn*Vkq;
        V[k][q] = sn*Vkp + c*Vkq;
    }
}

__device__ inline void svd3(const float A[9], float U[9], float sv[3], float V[9]) {
    float S[3][3];
    #pragma unroll
    for (int i = 0; i < 3; ++i)
        #pragma unroll
        for (int j = 0; j < 3; ++j) {
            float acc = 0.f;
            #pragma unroll
            for (int k = 0; k < 3; ++k) acc += A[k*3+i]*A[k*3+j];
            S[i][j] = acc;
        }
    float Vm[3][3] = {{1.f,0.f,0.f},{0.f,1.f,0.f},{0.f,0.f,1.f}};
    #pragma unroll
    for (int sweep = 0; sweep < 4; ++sweep) {
        jacobi_rot(S, Vm, 0, 1);
        jacobi_rot(S, Vm, 0, 2);
        jacobi_rot(S, Vm, 1, 2);
    }
    float lam[3] = {S[0][0], S[1][1], S[2][2]};
    int i0 = 0, i1 = 1, i2 = 2, t;
    if (lam[i0] < lam[i1]) { t = i0; i0 = i1; i1 = t; }
    if (lam[i0] < lam[i2]) { t = i0; i0 = i2; i2 = t; }
    if (lam[i1] < lam[i2]) { t = i1; i1 = i2; i2 = t; }
    int ord[3] = {i0, i1, i2};
    #pragma unroll
    for (int c = 0; c < 3; ++c) {
        int s_ = ord[c];
        float l = fmaxf(lam[s_], 0.f);
        float sval = sqrtf(l);
        sv[c] = sval;
        float v0 = Vm[0][s_], v1 = Vm[1][s_], v2 = Vm[2][s_];
        V[0*3+c] = v0; V[1*3+c] = v1; V[2*3+c] = v2;
        float inv = (sval > 1e-12f) ? 1.0f/sval : 0.f;
        U[0*3+c] = (A[0]*v0 + A[1]*v1 + A[2]*v2)*inv;
        U[1*3+c] = (A[3]*v0 + A[4]*v1 + A[5]*v2)*inv;
        U[2*3+c] = (A[6]*v0 + A[7]*v1 + A[8]*v2)*inv;
    }
}

// ---------------- binning helpers ----------------
__device__ inline void particle_base(float px, float py, float pz,
                                     int& bi, int& bj, int& bk,
                                     float& fx0, float& fx1, float& fx2) {
    float bxf = floorf(px*c_INV_DX - 0.5f);
    float byf = floorf(py*c_INV_DX - 0.5f);
    float bzf = floorf(pz*c_INV_DX - 0.5f);
    bi = (int)bxf; bj = (int)byf; bk = (int)bzf;
    bi = min(max(bi, 0), NG-3); bj = min(max(bj, 0), NG-3); bk = min(max(bk, 0), NG-3);
    fx0 = px*c_INV_DX - bxf;
    fx1 = py*c_INV_DX - byf;
    fx2 = pz*c_INV_DX - bzf;
}

__global__ void __launch_bounds__(256)
count_kernel(const float* __restrict__ x, int* __restrict__ tile_count, int N) {
    int n = blockIdx.x*256 + threadIdx.x;
    if (n >= N) return;
    int bi, bj, bk; float f0, f1, f2;
    particle_base(x[3*n+0], x[3*n+1], x[3*n+2], bi, bj, bk, f0, f1, f2);
    int tile = ((bi >> 3)*NT + (bj >> 3))*NT + (bk >> 3);
    atomicAdd(&tile_count[tile], 1);
}

// exclusive scan of 4096 tile counts, single block of 256 threads x 16 elems
__global__ void __launch_bounds__(256)
scan_kernel(const int* __restrict__ count, int* __restrict__ offset) {
    __shared__ int part[256];
    int t = threadIdx.x;
    int base = t*16;
    int local[16];
    int s = 0;
    #pragma unroll
    for (int i = 0; i < 16; ++i) { local[i] = s; s += count[base+i]; }
    part[t] = s;
    __syncthreads();
    for (int off = 1; off < 256; off <<= 1) {
        int v = (t >= off) ? part[t-off] : 0;
        __syncthreads();
        part[t] += v;
        __syncthreads();
    }
    int prev = (t == 0) ? 0 : part[t-1];
    #pragma unroll
    for (int i = 0; i < 16; ++i) offset[base+i] = prev + local[i];
    if (t == 255) offset[NTILES] = prev + s;
}

// ---------------- pre-pass: all per-particle math, coalesced reads ----------------
__global__ void __launch_bounds__(256)
pre_kernel(const float* __restrict__ x, const float* __restrict__ v,
           const float* __restrict__ Cin, const float* __restrict__ Fin,
           const float* __restrict__ Jp_in, const int* __restrict__ material,
           const int* __restrict__ offset, int* __restrict__ cursor,
           PRec* __restrict__ rec, int* __restrict__ sorted,
           float* __restrict__ out, int N) {
    int n = blockIdx.x*256 + threadIdx.x;
    if (n >= N) return;

    float px = x[3*n+0], py = x[3*n+1], pz = x[3*n+2];
    int bi, bj, bk; float f0, f1, f2;
    particle_base(px, py, pz, bi, bj, bk, f0, f1, f2);

    float Cm[9], Fm[9];
    #pragma unroll
    for (int i = 0; i < 9; ++i) { Cm[i] = Cin[9*n+i]; Fm[i] = Fin[9*n+i]; }

    // Fn = (I + DT*C) @ F
    float Fn[9];
    #pragma unroll
    for (int i = 0; i < 3; ++i)
        #pragma unroll
        for (int k = 0; k < 3; ++k) {
            float acc = Fm[i*3+k];
            #pragma unroll
            for (int j = 0; j < 3; ++j) acc += DT * Cm[i*3+j] * Fm[j*3+k];
            Fn[i*3+k] = acc;
        }

    float Jp = Jp_in[n];
    int mat = material[n];
    float h = expf(10.0f*(1.0f - Jp));
    h = fminf(fmaxf(h, 0.1f), 5.0f);
    if (mat == 1) h = 0.3f;
    float mu = (mat == 0) ? 0.0f : MU0*h;
    float la = LAM0*h;

    float U[9], V[9], sv[3];
    svd3(Fn, U, sv, V);

    float J = 1.0f;
    float sig[3];
    #pragma unroll
    for (int d = 0; d < 2; ++d) {
        float s = sv[d];
        float ns = (mat == 2) ? fminf(fmaxf(s, 1.0f-0.025f), 1.0f+0.0045f) : s;
        Jp = Jp * s / ns;
        sig[d] = ns;
        J *= ns;
    }
    sig[2] = sv[2];

    if (mat == 0) {
        float sj = sqrtf(J);
        Fn[0]=sj; Fn[1]=0; Fn[2]=0; Fn[3]=0; Fn[4]=sj; Fn[5]=0; Fn[6]=0; Fn[7]=0; Fn[8]=sj;
    } else if (mat == 2) {
        #pragma unroll
        for (int i = 0; i < 3; ++i)
            #pragma unroll
            for (int k = 0; k < 3; ++k) {
                float acc = 0.f;
                #pragma unroll
                for (int j = 0; j < 3; ++j) acc += U[i*3+j]*sig[j]*V[k*3+j];
                Fn[i*3+k] = acc;
            }
    }

    float R[9];
    #pragma unroll
    for (int i = 0; i < 3; ++i)
        #pragma unroll
        for (int k = 0; k < 3; ++k) {
            float acc = 0.f;
            #pragma unroll
            for (int j = 0; j < 3; ++j) acc += U[i*3+j]*V[k*3+j];
            R[i*3+k] = acc;
        }

    float press = la * J * (J - 1.0f);
    float scale = -DT * P_VOL * 4.0f * c_INV_DX * c_INV_DX;
    float aff[9];
    #pragma unroll
    for (int i = 0; i < 3; ++i)
        #pragma unroll
        for (int k = 0; k < 3; ++k) {
            float acc = 0.f;
            #pragma unroll
            for (int j = 0; j < 3; ++j) acc += (Fn[i*3+j]-R[i*3+j])*Fn[k*3+j];
            acc = 2.0f*mu*acc;
            if (i == k) acc += press;
            aff[i*3+k] = scale*acc + P_MASS*Cm[i*3+k];
        }

    float* po = out + (size_t)n*25;
    po[6] = Jp;
    #pragma unroll
    for (int i = 0; i < 9; ++i) po[7+i] = Fn[i];

    // sorted slot
    int tile = ((bi >> 3)*NT + (bj >> 3))*NT + (bk >> 3);
    int pos = offset[tile] + atomicAdd(&cursor[tile], 1);
    sorted[pos] = n;

    // one full 64-B line, written with 4x float4
    float4* rp = (float4*)&rec[pos];
    float4 r0; r0.x = px; r0.y = py; r0.z = pz;
    int basep = bi | (bj << 7) | (bk << 14);
    r0.w = __int_as_float(basep);
    rp[0] = r0;
    rp[1] = make_float4(aff[0], aff[1], aff[2], aff[3]);
    rp[2] = make_float4(aff[4], aff[5], aff[6], aff[7]);
    rp[3] = make_float4(aff[8], P_MASS*v[3*n+0], P_MASS*v[3*n+1], P_MASS*v[3*n+2]);
}

// ---------------- P2G (tiled, LDS accumulate, coalesced record reads) ----------------
__global__ void __launch_bounds__(256)
p2g_tile_kernel(const PRec* __restrict__ rec, const int* __restrict__ offset,
                float4* __restrict__ grid) {
    int tile = blockIdx.x;
    int beg = offset[tile], end = offset[tile+1];
    if (beg == end) return;

    __shared__ float lds[4][1000];   // SoA: [comp][10*10*10 halo cells]
    for (int c = threadIdx.x; c < 1000; c += 256) {
        lds[0][c] = 0.f; lds[1][c] = 0.f; lds[2][c] = 0.f; lds[3][c] = 0.f;
    }
    __syncthreads();

    int tx8 = (tile / (NT*NT)) << 3;
    int ty8 = ((tile / NT) % NT) << 3;
    int tz8 = (tile % NT) << 3;

    for (int p = beg + (int)threadIdx.x; p < end; p += 256) {
        const float4* rp = (const float4*)&rec[p];
        float4 r0 = rp[0];
        float4 r1 = rp[1];
        float4 r2 = rp[2];
        float4 r3 = rp[3];

        int basep = __float_as_int(r0.w);
        int bi = basep & 127, bj = (basep >> 7) & 127, bk = (basep >> 14) & 127;
        float fx0 = r0.x*c_INV_DX - floorf(r0.x*c_INV_DX - 0.5f);
        float fx1 = r0.y*c_INV_DX - floorf(r0.y*c_INV_DX - 0.5f);
        float fx2 = r0.z*c_INV_DX - floorf(r0.z*c_INV_DX - 0.5f);

        float wx[3], wy[3];
        wx[0] = 0.5f*(1.5f-fx0)*(1.5f-fx0); wx[1] = 0.75f-(fx0-1.f)*(fx0-1.f); wx[2] = 0.5f*(fx0-0.5f)*(fx0-0.5f);
        wy[0] = 0.5f*(1.5f-fx1)*(1.5f-fx1); wy[1] = 0.75f-(fx1-1.f)*(fx1-1.f); wy[2] = 0.5f*(fx1-0.5f)*(fx1-0.5f);

        float a0 = r1.x, a1 = r1.y, a2 = r1.z, a3 = r1.w;
        float a4 = r2.x, a5 = r2.y, a6 = r2.z, a7 = r2.w;
        float a8 = r3.x, mv0 = r3.y, mv1 = r3.z, mv2 = r3.w;

        int offi = bi - tx8, offj = bj - ty8, offk = bk - tz8;
        #pragma unroll
        for (int i = 0; i < 3; ++i) {
            float dpx = ((float)i - fx0)*c_DX;
            #pragma unroll
            for (int j = 0; j < 3; ++j) {
                float wgt = wx[i]*wy[j];     // reference uses only x,y weight factors
                float dpy = ((float)j - fx1)*c_DX;
                int c0 = ((offi+i)*10 + (offj+j))*10 + offk;
                float wm = wgt*P_MASS;
                #pragma unroll
                for (int k = 0; k < 3; ++k) {
                    float dpz = ((float)k - fx2)*c_DX;
                    float mx = wgt*(mv0 + a0*dpx + a1*dpy + a2*dpz);
                    float my = wgt*(mv1 + a3*dpx + a4*dpy + a5*dpz);
                    float mz = wgt*(mv2 + a6*dpx + a7*dpy + a8*dpz);
                    int c = c0 + k;
                    atomicAdd(&lds[0][c], mx);
                    atomicAdd(&lds[1][c], my);
                    atomicAdd(&lds[2][c], mz);
                    atomicAdd(&lds[3][c], wm);
                }
            }
        }
    }
    __syncthreads();

    // dense flush of the 10x10x10 halo region
    for (int c = threadIdx.x; c < 1000; c += 256) {
        float gm = lds[3][c];
        float gx = lds[0][c], gy = lds[1][c], gz = lds[2][c];
        if (gm != 0.f || gx != 0.f || gy != 0.f || gz != 0.f) {
            int ci = c / 100, cj = (c / 10) % 10, ck = c % 10;
            int gi = tx8 + ci, gj = ty8 + cj, gk = tz8 + ck;
            if (gi < NG && gj < NG && gk < NG) {
                float* cp = (float*)&grid[(gi*NG + gj)*NG + gk];
                atomicAdd(cp+0, gx);
                atomicAdd(cp+1, gy);
                atomicAdd(cp+2, gz);
                atomicAdd(cp+3, gm);
            }
        }
    }
}

// ---------------- grid update ----------------
__global__ void __launch_bounds__(256)
grid_kernel(float4* __restrict__ grid, const float* __restrict__ gravity,
            const float* __restrict__ attr_s, const float* __restrict__ attr_p) {
    int g = blockIdx.x * 256 + threadIdx.x;
    if (g >= G3) return;
    float4 cell = grid[g];
    float m = cell.w;
    float gvx = 0.f, gvy = 0.f, gvz = 0.f;
    if (m > 0.f) {
        float inv = 1.0f/m;
        gvx = cell.x*inv; gvy = cell.y*inv; gvz = cell.z*inv;
        gvx += DT * gravity[0] * 30.0f;
        gvy += DT * gravity[1] * 30.0f;
        gvz += DT * gravity[2] * 30.0f;
        int k = g & (NG-1);
        int j = (g >> 7) & (NG-1);
        int i = g >> 14;
        float dx_ = attr_p[0] - c_DX*(float)i;
        float dy_ = attr_p[1] - c_DX*(float)j;
        float dz_ = attr_p[2] - c_DX*(float)k;
        float nrm = sqrtf(dx_*dx_ + dy_*dy_ + dz_*dz_);
        float sc = attr_s[0] * DT * 100.0f / (0.01f + nrm);
        gvx += dx_*sc; gvy += dy_*sc; gvz += dz_*sc;
        if (i < 3      && gvx < 0.f) gvx = 0.f;
        if (i > NG-3   && gvx > 0.f) gvx = 0.f;
        if (j < 3      && gvy < 0.f) gvy = 0.f;
        if (j > NG-3   && gvy > 0.f) gvy = 0.f;
    }
    grid[g] = make_float4(gvx, gvy, gvz, m);
}

// ---------------- G2P (sorted order, coalesced record reads) ----------------
__global__ void __launch_bounds__(256)
g2p_kernel(const PRec* __restrict__ rec, const int* __restrict__ sorted,
           const float4* __restrict__ grid, float* __restrict__ out, int N) {
    int gid = blockIdx.x * 256 + threadIdx.x;
    if (gid >= N) return;
    int n = sorted[gid];

    const float4* rp = (const float4*)&rec[gid];
    float4 r0 = rp[0];
    float px = r0.x, py = r0.y, pz = r0.z;
    int basep = __float_as_int(r0.w);
    int bi = basep & 127, bj = (basep >> 7) & 127, bk = (basep >> 14) & 127;
    float fx0 = px*c_INV_DX - floorf(px*c_INV_DX - 0.5f);
    float fx1 = py*c_INV_DX - floorf(py*c_INV_DX - 0.5f);
    float fx2 = pz*c_INV_DX - floorf(pz*c_INV_DX - 0.5f);

    float wx[3], wy[3];
    wx[0] = 0.5f*(1.5f-fx0)*(1.5f-fx0); wx[1] = 0.75f-(fx0-1.f)*(fx0-1.f); wx[2] = 0.5f*(fx0-0.5f)*(fx0-0.5f);
    wy[0] = 0.5f*(1.5f-fx1)*(1.5f-fx1); wy[1] = 0.75f-(fx1-1.f)*(fx1-1.f); wy[2] = 0.5f*(fx1-0.5f)*(fx1-0.5f);

    float nvx = 0.f, nvy = 0.f, nvz = 0.f;
    float nC[9];
    #pragma unroll
    for (int i = 0; i < 9; ++i) nC[i] = 0.f;

    #pragma unroll
    for (int i = 0; i < 3; ++i) {
        float dpx = (float)i - fx0;
        #pragma unroll
        for (int j = 0; j < 3; ++j) {
            float wgt = wx[i]*wy[j];
            float dpy = (float)j - fx1;
            int cell0 = ((bi+i)*NG + (bj+j))*NG + bk;
            #pragma unroll
            for (int k = 0; k < 3; ++k) {
                float dpz = (float)k - fx2;
                float4 gv = grid[cell0 + k];
                float wgx = wgt*gv.x, wgy = wgt*gv.y, wgz = wgt*gv.z;
                nvx += wgx; nvy += wgy; nvz += wgz;
                nC[0] += wgx*dpx; nC[1] += wgx*dpy; nC[2] += wgx*dpz;
                nC[3] += wgy*dpx; nC[4] += wgy*dpy; nC[5] += wgy*dpz;
                nC[6] += wgz*dpx; nC[7] += wgz*dpy; nC[8] += wgz*dpz;
            }
        }
    }

    float* po = out + (size_t)n*25;
    po[0] = px + DT*nvx;
    po[1] = py + DT*nvy;
    po[2] = pz + DT*nvz;
    po[3] = nvx; po[4] = nvy; po[5] = nvz;
    float s4 = 4.0f*c_INV_DX;
    #pragma unroll
    for (int i = 0; i < 9; ++i) po[16+i] = s4*nC[i];
}

extern "C" void kernel_launch(void* const* d_in, const int* in_sizes, int n_in,
                              void* d_out, int out_size, void* d_ws, size_t ws_size,
                              hipStream_t stream) {
    const float* x        = (const float*)d_in[0];
    const float* v        = (const float*)d_in[1];
    const float* C        = (const float*)d_in[2];
    const float* F        = (const float*)d_in[3];
    const float* Jp       = (const float*)d_in[4];
    const float* gravity  = (const float*)d_in[5];
    const float* attr_s   = (const float*)d_in[6];
    const float* attr_p   = (const float*)d_in[7];
    const int*   material = (const int*)d_in[8];
    float* out = (float*)d_out;
    int N = in_sizes[0] / 3;

    // workspace layout: [grid][tile_count][cursor][tile_offset][sorted][records]
    char* ws = (char*)d_ws;
    float4* grid      = (float4*)ws;                       size_t o = (size_t)G3*sizeof(float4);
    int* tile_count   = (int*)(ws + o);                    o += NTILES*sizeof(int);
    int* cursor       = (int*)(ws + o);                    o += NTILES*sizeof(int);
    size_t zero_bytes = o;                                 // grid + counts + cursor zeroed in one memset
    int* tile_offset  = (int*)(ws + o);                    o += (NTILES+1)*sizeof(int);
    int* sorted       = (int*)(ws + o);                    o += (size_t)N*sizeof(int);
    o = (o + 63) & ~(size_t)63;                            // 64-B align records
    PRec* rec         = (PRec*)(ws + o);                   o += (size_t)N*sizeof(PRec);

    hipMemsetAsync(d_ws, 0, zero_bytes, stream);

    int pblocks = (N + 255) / 256;
    count_kernel<<<pblocks, 256, 0, stream>>>(x, tile_count, N);
    scan_kernel<<<1, 256, 0, stream>>>(tile_count, tile_offset);
    pre_kernel<<<pblocks, 256, 0, stream>>>(x, v, C, F, Jp, material,
                                            tile_offset, cursor, rec, sorted, out, N);
    p2g_tile_kernel<<<NTILES, 256, 0, stream>>>(rec, tile_offset, grid);
    grid_kernel<<<G3/256, 256, 0, stream>>>(grid, gravity, attr_s, attr_p);
    g2p_kernel<<<pblocks, 256, 0, stream>>>(rec, sorted, grid, out, N);
}